// Round 9
// baseline (365.460 us; speedup 1.0000x reference)
//
#include <hip/hip_runtime.h>

#define HID 128
#define INP 64
#define LN_EPS 1e-5f
#define RT 64    // rows per block in GEMM kernels
#define SCAP 1024  // per-slice bucket capacity (expected ~256)

typedef __attribute__((ext_vector_type(8))) short bf16x8;
typedef __attribute__((ext_vector_type(4))) float f32x4;

__device__ __forceinline__ unsigned f2bf(float f) {
    unsigned u = __float_as_uint(f);
    return (u + 0x7FFFu + ((u >> 16) & 1u)) >> 16;   // RNE
}
__device__ __forceinline__ float bflo(unsigned v) { return __uint_as_float(v << 16); }
__device__ __forceinline__ float bfhi(unsigned v) { return __uint_as_float(v & 0xFFFF0000u); }

// ---------------- CSR count (16 edges/thread) + fused weight prep ----------------
__global__ __launch_bounds__(256) void k_count(const int* __restrict__ dst, int nE, int* __restrict__ cnt,
                                               int nEdgeThreads,
                                               const float* __restrict__ W_in, const float* __restrict__ W_l,
                                               unsigned short* __restrict__ Wt_in, unsigned short* __restrict__ Wt_l) {
    int t = blockIdx.x * 256 + threadIdx.x;
    if (t < nEdgeThreads) {
        int base = t * 16;
        if (base + 16 <= nE) {
#pragma unroll
            for (int j = 0; j < 4; ++j) {
                int4 d = *reinterpret_cast<const int4*>(dst + base + j * 4);
                atomicAdd(&cnt[d.x], 1);
                atomicAdd(&cnt[d.y], 1);
                atomicAdd(&cnt[d.z], 1);
                atomicAdd(&cnt[d.w], 1);
            }
        } else {
            for (int e = base; e < nE; ++e) atomicAdd(&cnt[dst[e]], 1);
        }
        return;
    }
    int i = t - nEdgeThreads;
    if (i < 128 * 64) {
        int col = i >> 6, k = i & 63;
        Wt_in[i] = (unsigned short)f2bf(W_in[(size_t)k * HID + col]);
    } else if (i < 128 * 64 + 3 * 128 * 128) {
        int j = i - 128 * 64;
        int l = j >> 14, r = j & 16383;
        int col = r >> 7, k = r & 127;
        Wt_l[j] = (unsigned short)f2bf(W_l[(size_t)l * 16384 + (size_t)k * HID + col]);
    }
}

__global__ void k_scan1(const int* __restrict__ cnt, int n, int* __restrict__ rowp, int* __restrict__ bsum) {
    __shared__ int s[256];
    int i = blockIdx.x * 256 + threadIdx.x;
    int v = (i < n) ? cnt[i] : 0;
    s[threadIdx.x] = v;
    __syncthreads();
    for (int off = 1; off < 256; off <<= 1) {
        int t = (threadIdx.x >= off) ? s[threadIdx.x - off] : 0;
        __syncthreads();
        s[threadIdx.x] += t;
        __syncthreads();
    }
    if (i < n) rowp[i] = s[threadIdx.x] - v;  // exclusive
    if (threadIdx.x == 255) bsum[blockIdx.x] = s[255];
}

__global__ void k_scan2(int* __restrict__ bsum, int nb) {
    __shared__ int s[256];
    int v = (threadIdx.x < nb) ? bsum[threadIdx.x] : 0;
    s[threadIdx.x] = v;
    __syncthreads();
    for (int off = 1; off < 256; off <<= 1) {
        int t = (threadIdx.x >= off) ? s[threadIdx.x - off] : 0;
        __syncthreads();
        s[threadIdx.x] += t;
        __syncthreads();
    }
    if (threadIdx.x < nb) bsum[threadIdx.x] = s[threadIdx.x] - v;
}

__global__ void k_scan3(int* __restrict__ rowp, const int* __restrict__ bsum, const int* __restrict__ cnt,
                        int n, int nE, int* __restrict__ cursor, float* __restrict__ invd) {
    int i = blockIdx.x * 256 + threadIdx.x;
    if (i < n) {
        int rp = rowp[i] + bsum[blockIdx.x];
        rowp[i] = rp;
        cursor[i] = rp;
        int c = cnt[i];
        invd[i] = 1.0f / (float)(c > 1 ? c : 1);
    } else if (i == n) {
        rowp[n] = nE;
    }
}

// ---------------- bucketed CSR fill ----------------
// Pass A: scatter (src,dst) into 128-node-range buckets, per-(bucket, blockIdx&7) append slices.
__global__ __launch_bounds__(256) void k_bucket(const int* __restrict__ src, const int* __restrict__ dst, int nE,
                                                int* __restrict__ bcur, int2* __restrict__ bbuf,
                                                int* __restrict__ cursor, int* __restrict__ csrc) {
    int t = blockIdx.x * 256 + threadIdx.x;
    int base = t * 8;
    int slice = blockIdx.x & 7;
    if (base + 8 <= nE) {
        int4 d0 = *reinterpret_cast<const int4*>(dst + base);
        int4 d1 = *reinterpret_cast<const int4*>(dst + base + 4);
        int4 s0 = *reinterpret_cast<const int4*>(src + base);
        int4 s1 = *reinterpret_cast<const int4*>(src + base + 4);
        int ds[8] = {d0.x, d0.y, d0.z, d0.w, d1.x, d1.y, d1.z, d1.w};
        int ss[8] = {s0.x, s0.y, s0.z, s0.w, s1.x, s1.y, s1.z, s1.w};
#pragma unroll
        for (int j = 0; j < 8; ++j) {
            int b = ds[j] >> 7;
            int pos = atomicAdd(&bcur[b * 8 + slice], 1);
            if (pos < SCAP) {
                bbuf[((size_t)(b * 8 + slice)) * SCAP + pos] = make_int2(ss[j], ds[j]);
            } else {  // overflow fallback: direct scatter (correct for any distribution)
                int p = atomicAdd(&cursor[ds[j]], 1);
                csrc[p] = ss[j];
            }
        }
    } else if (base < nE) {
        for (int e = base; e < nE; ++e) {
            int d = dst[e], s = src[e];
            int b = d >> 7;
            int pos = atomicAdd(&bcur[b * 8 + slice], 1);
            if (pos < SCAP) {
                bbuf[((size_t)(b * 8 + slice)) * SCAP + pos] = make_int2(s, d);
            } else {
                int p = atomicAdd(&cursor[d], 1);
                csrc[p] = s;
            }
        }
    }
}

// Pass B: drain slices; 2 blocks per bucket (slices 0-3 / 4-7); stores land in the
// bucket's contiguous ~8KB csrc window -> full line combining.
__global__ __launch_bounds__(256) void k_fill2(const int* __restrict__ bcur, const int2* __restrict__ bbuf,
                                               int* __restrict__ cursor, int* __restrict__ csrc) {
    int b = blockIdx.x >> 1;
    int s0 = (blockIdx.x & 1) * 4;
    for (int slice = s0; slice < s0 + 4; ++slice) {
        int cnt = bcur[b * 8 + slice];
        if (cnt > SCAP) cnt = SCAP;
        for (int e = threadIdx.x; e < cnt; e += 256) {
            int2 sd = bbuf[((size_t)(b * 8 + slice)) * SCAP + e];
            int p = atomicAdd(&cursor[sd.y], 1);
            csrc[p] = sd.x;
        }
    }
}

// ---------------- in-projection (MFMA): hb = bf16(x @ W_in + b_in) ----------------
__global__ __launch_bounds__(256) void k_inproj(const float* __restrict__ x,
                                                const unsigned short* __restrict__ Wt,  // [128][64] bf16
                                                const float* __restrict__ b,
                                                unsigned* __restrict__ hout, int n) {
    __shared__ unsigned short xs[RT * INP];  // 8 KB, swizzled
    const int tid = threadIdx.x;
    const int row0 = blockIdx.x * RT;

#pragma unroll
    for (int j = 0; j < 2; ++j) {
        int fid = tid + j * 256;
        int r = fid >> 3, c = fid & 7;
        int grow = row0 + r;
        unsigned o[4] = {0, 0, 0, 0};
        if (grow < n) {
            float4 v0 = *reinterpret_cast<const float4*>(x + (size_t)grow * INP + c * 8);
            float4 v1 = *reinterpret_cast<const float4*>(x + (size_t)grow * INP + c * 8 + 4);
            o[0] = f2bf(v0.x) | (f2bf(v0.y) << 16);
            o[1] = f2bf(v0.z) | (f2bf(v0.w) << 16);
            o[2] = f2bf(v1.x) | (f2bf(v1.y) << 16);
            o[3] = f2bf(v1.z) | (f2bf(v1.w) << 16);
        }
        int sw = c ^ (r & 7);
        *reinterpret_cast<uint4*>(xs + r * INP + sw * 8) = make_uint4(o[0], o[1], o[2], o[3]);
    }
    __syncthreads();

    const int l = tid & 63;
    const int w = tid >> 6;
    const int l15 = l & 15, lg = l >> 4;
    const int xrow = w * 16 + l15;

    f32x4 acc[8];
#pragma unroll
    for (int t = 0; t < 8; ++t) acc[t] = (f32x4){0.f, 0.f, 0.f, 0.f};

#pragma unroll
    for (int kc = 0; kc < 2; ++kc) {
        int bc = (kc * 4 + lg) ^ (xrow & 7);
        bf16x8 bfrag = *reinterpret_cast<const bf16x8*>(xs + xrow * INP + bc * 8);
        const unsigned short* wp = Wt + (size_t)l15 * INP + kc * 32 + lg * 8;
        bf16x8 af[8];
#pragma unroll
        for (int t = 0; t < 8; ++t) af[t] = *reinterpret_cast<const bf16x8*>(wp + (size_t)t * 16 * INP);
#pragma unroll
        for (int t = 0; t < 8; ++t)
            acc[t] = __builtin_amdgcn_mfma_f32_16x16x32_bf16(af[t], bfrag, acc[t], 0, 0, 0);
    }

    int grow = row0 + xrow;
    if (grow < n) {
#pragma unroll
        for (int t = 0; t < 8; ++t) {
            int c0 = t * 16 + lg * 4;
            f32x4 bb = *reinterpret_cast<const f32x4*>(b + c0);
            f32x4 o = acc[t] + bb;
            uint2 p;
            p.x = f2bf(o.x) | (f2bf(o.y) << 16);
            p.y = f2bf(o.z) | (f2bf(o.w) << 16);
            *reinterpret_cast<uint2*>(hout + (size_t)grow * 64 + t * 8 + lg * 2) = p;
        }
    }
}

// ---------------- aggregation: aggx[v] = bf16( hb[v] + (sum_{u in N(v)} hb[u]) * invd[v] ), PRE-SWIZZLED ----------------
// one wave per node; lane-parallel index prefetch + __shfl broadcast -> all gathers in flight
__global__ __launch_bounds__(256) void k_agg(const unsigned* __restrict__ hb, const int* __restrict__ rowp,
                                             const int* __restrict__ csrc, const float* __restrict__ invd,
                                             unsigned* __restrict__ aggx, int n) {
    int node = blockIdx.x * 4 + (threadIdx.x >> 6);
    if (node >= n) return;
    int lane = threadIdx.x & 63;
    int e0 = rowp[node], e1 = rowp[node + 1];
    int deg = e1 - e0;
    unsigned self = hb[(size_t)node * 64 + lane];
    float inv = invd[node];
    float ax = 0.f, ay = 0.f;

    for (int base = 0; base < deg; base += 64) {
        int m = deg - base;
        if (m > 64) m = 64;
        int myidx = (base + lane < deg) ? csrc[e0 + base + lane] : 0;
        int j = 0;
        for (; j + 8 <= m; j += 8) {
            int s0 = __shfl(myidx, j + 0);
            int s1 = __shfl(myidx, j + 1);
            int s2 = __shfl(myidx, j + 2);
            int s3 = __shfl(myidx, j + 3);
            int s4 = __shfl(myidx, j + 4);
            int s5 = __shfl(myidx, j + 5);
            int s6 = __shfl(myidx, j + 6);
            int s7 = __shfl(myidx, j + 7);
            unsigned v0 = hb[(size_t)s0 * 64 + lane];
            unsigned v1 = hb[(size_t)s1 * 64 + lane];
            unsigned v2 = hb[(size_t)s2 * 64 + lane];
            unsigned v3 = hb[(size_t)s3 * 64 + lane];
            unsigned v4 = hb[(size_t)s4 * 64 + lane];
            unsigned v5 = hb[(size_t)s5 * 64 + lane];
            unsigned v6 = hb[(size_t)s6 * 64 + lane];
            unsigned v7 = hb[(size_t)s7 * 64 + lane];
            ax += ((bflo(v0) + bflo(v1)) + (bflo(v2) + bflo(v3))) +
                  ((bflo(v4) + bflo(v5)) + (bflo(v6) + bflo(v7)));
            ay += ((bfhi(v0) + bfhi(v1)) + (bfhi(v2) + bfhi(v3))) +
                  ((bfhi(v4) + bfhi(v5)) + (bfhi(v6) + bfhi(v7)));
        }
        for (; j < m; ++j) {
            int s0 = __shfl(myidx, j);
            unsigned v = hb[(size_t)s0 * 64 + lane];
            ax += bflo(v);
            ay += bfhi(v);
        }
    }

    float xlo = bflo(self) + ax * inv;
    float xhi = bfhi(self) + ay * inv;
    unsigned o = f2bf(xlo) | (f2bf(xhi) << 16);
    // swizzled position: 16B chunk c -> c ^ (row&7), within the same 256B row
    int c = lane >> 2;
    int sw = c ^ (node & 7);
    aggx[(size_t)node * 64 + sw * 4 + (lane & 3)] = o;
}

// ---------------- layer MFMA (no LDS): hout = relu(LN(X@W + b)*g + lnb) + hin ----------------
__global__ __launch_bounds__(256) void k_layer(const unsigned* __restrict__ hin,   // residual, [n*64] bf16 pairs
                                               unsigned* __restrict__ hout,
                                               const unsigned* __restrict__ aggx,  // pre-swizzled X (padded)
                                               const unsigned short* __restrict__ Wt,  // [128][128] bf16
                                               const float* __restrict__ bias, const float* __restrict__ g,
                                               const float* __restrict__ lnb, int n) {
    const int tid = threadIdx.x;
    const int row0 = blockIdx.x * RT;
    const int lane = tid & 63;
    const int w = tid >> 6;
    const int l15 = lane & 15, lg = lane >> 4;
    const int xrow = w * 16 + l15;
    const int grow = row0 + xrow;   // may be >= n for tail block; aggx is padded

    const unsigned short* xg = reinterpret_cast<const unsigned short*>(aggx) + (size_t)grow * HID;

    f32x4 acc[8];
#pragma unroll
    for (int t = 0; t < 8; ++t) acc[t] = (f32x4){0.f, 0.f, 0.f, 0.f};

#pragma unroll
    for (int kc = 0; kc < 4; ++kc) {
        int bc = (kc * 4 + lg) ^ (xrow & 7);
        bf16x8 bfrag = *reinterpret_cast<const bf16x8*>(xg + bc * 8);
        const unsigned short* wp = Wt + (size_t)l15 * HID + kc * 32 + lg * 8;
        bf16x8 af[8];
#pragma unroll
        for (int t = 0; t < 8; ++t) af[t] = *reinterpret_cast<const bf16x8*>(wp + (size_t)t * 16 * HID);
#pragma unroll
        for (int t = 0; t < 8; ++t)
            acc[t] = __builtin_amdgcn_mfma_f32_16x16x32_bf16(af[t], bfrag, acc[t], 0, 0, 0);
    }

    float s = 0.f, q = 0.f;
#pragma unroll
    for (int t = 0; t < 8; ++t) {
        int c0 = t * 16 + lg * 4;
        f32x4 bb = *reinterpret_cast<const f32x4*>(bias + c0);
        acc[t] = acc[t] + bb;
        s += acc[t].x + acc[t].y + acc[t].z + acc[t].w;
        q += acc[t].x * acc[t].x + acc[t].y * acc[t].y + acc[t].z * acc[t].z + acc[t].w * acc[t].w;
    }
    s += __shfl_xor(s, 16, 64);
    s += __shfl_xor(s, 32, 64);
    q += __shfl_xor(q, 16, 64);
    q += __shfl_xor(q, 32, 64);
    float mu = s * (1.0f / HID);
    float var = q * (1.0f / HID) - mu * mu;
    float rs = rsqrtf(var + LN_EPS);

    if (grow < n) {
#pragma unroll
        for (int t = 0; t < 8; ++t) {
            int c0 = t * 16 + lg * 4;
            uint2 rv = *reinterpret_cast<const uint2*>(hin + (size_t)grow * 64 + t * 8 + lg * 2);
            f32x4 gv = *reinterpret_cast<const f32x4*>(g + c0);
            f32x4 lb = *reinterpret_cast<const f32x4*>(lnb + c0);
            float o0 = fmaxf((acc[t].x - mu) * rs * gv.x + lb.x, 0.f) + bflo(rv.x);
            float o1 = fmaxf((acc[t].y - mu) * rs * gv.y + lb.y, 0.f) + bfhi(rv.x);
            float o2 = fmaxf((acc[t].z - mu) * rs * gv.z + lb.z, 0.f) + bflo(rv.y);
            float o3 = fmaxf((acc[t].w - mu) * rs * gv.w + lb.w, 0.f) + bfhi(rv.y);
            uint2 p;
            p.x = f2bf(o0) | (f2bf(o1) << 16);
            p.y = f2bf(o2) | (f2bf(o3) << 16);
            *reinterpret_cast<uint2*>(hout + (size_t)grow * 64 + t * 8 + lg * 2) = p;
        }
    }
}

// ---------------- final: accum[c] = sum over rows < n_act of h[r][c] ----------------
__global__ __launch_bounds__(256) void k_rowsum(const unsigned* __restrict__ hb, const int* __restrict__ n_act_p,
                                                float* __restrict__ accum, int n) {
    __shared__ float sred[256 * 2];
    int na = *n_act_p;
    int row0 = blockIdx.x * 256;
    int c = threadIdx.x & 63;    // col pair
    int sub = threadIdx.x >> 6;  // 0..3
    int rend = row0 + 256;
    if (rend > na) rend = na;
    float sx = 0.f, sy = 0.f;
    for (int r = row0 + sub; r < rend; r += 4) {
        unsigned v = hb[(size_t)r * 64 + c];
        sx += bflo(v);
        sy += bfhi(v);
    }
    sred[threadIdx.x * 2] = sx;
    sred[threadIdx.x * 2 + 1] = sy;
    __syncthreads();
    if (threadIdx.x < 64) {
        float tx = sred[threadIdx.x * 2] + sred[(threadIdx.x + 64) * 2] +
                   sred[(threadIdx.x + 128) * 2] + sred[(threadIdx.x + 192) * 2];
        float ty = sred[threadIdx.x * 2 + 1] + sred[(threadIdx.x + 64) * 2 + 1] +
                   sred[(threadIdx.x + 128) * 2 + 1] + sred[(threadIdx.x + 192) * 2 + 1];
        if (row0 < na) {
            atomicAdd(&accum[2 * threadIdx.x], tx);
            atomicAdd(&accum[2 * threadIdx.x + 1], ty);
        }
    }
}

__global__ void k_out(const float* __restrict__ accum, const int* __restrict__ n_act_p,
                      const float* __restrict__ W_out, const float* __restrict__ b_out,
                      float* __restrict__ out) {
    __shared__ float m[HID];
    int c = threadIdx.x;
    float na = (float)(*n_act_p);
    m[c] = accum[c] / na;
    __syncthreads();
    float s = b_out[c];
    for (int k = 0; k < HID; ++k) s += m[k] * W_out[k * HID + c];
    out[c] = s;
}

extern "C" void kernel_launch(void* const* d_in, const int* in_sizes, int n_in,
                              void* d_out, int out_size, void* d_ws, size_t ws_size,
                              hipStream_t stream) {
    const int n  = in_sizes[0] / INP;   // 50000
    const int nE = in_sizes[1] / 2;     // 800000
    const float* x    = (const float*)d_in[0];
    const int*   ei   = (const int*)d_in[1];
    const int*   src  = ei;
    const int*   dst  = ei + nE;
    const int*   nact = (const int*)d_in[2];
    const float* W_in = (const float*)d_in[3];
    const float* b_in = (const float*)d_in[4];
    const float* W_l  = (const float*)d_in[5];
    const float* b_l  = (const float*)d_in[6];
    const float* lng  = (const float*)d_in[7];
    const float* lnb  = (const float*)d_in[8];
    const float* W_o  = (const float*)d_in[9];
    const float* b_o  = (const float*)d_in[10];

    char* ws = (char*)d_ws;
    size_t off = 0;
    auto alloc = [&](size_t bytes) {
        void* p = ws + off;
        off = (off + bytes + 255) & ~((size_t)255);
        return p;
    };
    const int nBuck = (n + 127) >> 7;   // 128-node buckets
    unsigned* hbA  = (unsigned*)alloc((size_t)n * 64 * 4);
    unsigned* hbB  = (unsigned*)alloc((size_t)n * 64 * 4);
    unsigned* aggx = (unsigned*)alloc((size_t)(n + RT) * 64 * 4);  // +RT rows pad for tail-block frag reads
    int*   cnt  = (int*)alloc((size_t)n * 4);
    int*   rowp = (int*)alloc((size_t)(n + 1) * 4);
    int*   curs = (int*)alloc((size_t)n * 4);
    float* invd = (float*)alloc((size_t)n * 4);
    int*   csrc = (int*)alloc((size_t)nE * 4);
    int*   bsum = (int*)alloc(1024);
    float* accum = (float*)alloc(HID * 4);
    unsigned short* Wt_in = (unsigned short*)alloc(128 * 64 * 2);
    unsigned short* Wt_l  = (unsigned short*)alloc(3 * 128 * 128 * 2);
    int*  bcur = (int*)alloc((size_t)nBuck * 8 * 4);
    int2* bbuf = (int2*)alloc((size_t)nBuck * 8 * SCAP * 8);

    hipMemsetAsync(cnt, 0, (size_t)n * 4, stream);
    hipMemsetAsync(accum, 0, HID * 4, stream);
    hipMemsetAsync(bcur, 0, (size_t)nBuck * 8 * 4, stream);

    int nb = (n + 255) / 256;
    int nEdgeThreads = (nE + 15) / 16;                       // 16 edges/thread
    int nPrep = 128 * 64 + 3 * 128 * 128;
    int cpgrid = (nEdgeThreads + nPrep + 255) / 256;
    k_count<<<cpgrid, 256, 0, stream>>>(dst, nE, cnt, nEdgeThreads, W_in, W_l, Wt_in, Wt_l);
    k_scan1<<<nb, 256, 0, stream>>>(cnt, n, rowp, bsum);
    k_scan2<<<1, 256, 0, stream>>>(bsum, nb);
    k_scan3<<<nb, 256, 0, stream>>>(rowp, bsum, cnt, n, nE, curs, invd);
    k_bucket<<<(nE / 8 + 255) / 256 + 1, 256, 0, stream>>>(src, dst, nE, bcur, bbuf, curs, csrc);
    k_fill2<<<nBuck * 2, 256, 0, stream>>>(bcur, bbuf, curs, csrc);

    int tgrid = (n + RT - 1) / RT;
    k_inproj<<<tgrid, 256, 0, stream>>>(x, Wt_in, b_in, hbA, n);

    const unsigned* hin = hbA;
    unsigned* hout = hbB;
    for (int l = 0; l < 3; ++l) {
        k_agg<<<(n + 3) / 4, 256, 0, stream>>>(hin, rowp, csrc, invd, aggx, n);
        k_layer<<<tgrid, 256, 0, stream>>>(hin, hout, aggx,
                                           Wt_l + (size_t)l * 128 * 128,
                                           b_l + l * HID, lng + l * HID, lnb + l * HID, n);
        const unsigned* t = hout;
        hout = (unsigned*)hin;
        hin = t;
    }
    k_rowsum<<<(n + 255) / 256, 256, 0, stream>>>(hin, nact, accum, n);
    k_out<<<1, HID, 0, stream>>>(accum, nact, W_o, b_o, (float*)d_out);
}

// Round 10
// 294.005 us; speedup vs baseline: 1.2430x; 1.2430x over previous
//
#include <hip/hip_runtime.h>

#define HID 128
#define INP 64
#define LN_EPS 1e-5f
#define RT 64   // rows per block in GEMM kernels

typedef __attribute__((ext_vector_type(8))) short bf16x8;
typedef __attribute__((ext_vector_type(4))) float f32x4;

__device__ __forceinline__ unsigned f2bf(float f) {
    unsigned u = __float_as_uint(f);
    return (u + 0x7FFFu + ((u >> 16) & 1u)) >> 16;   // RNE
}
__device__ __forceinline__ float bflo(unsigned v) { return __uint_as_float(v << 16); }
__device__ __forceinline__ float bfhi(unsigned v) { return __uint_as_float(v & 0xFFFF0000u); }

// ---------------- CSR count (16 edges/thread, records per-edge rank) + fused weight prep ----------------
__global__ __launch_bounds__(256) void k_count(const int* __restrict__ dst, int nE, int* __restrict__ cnt,
                                               int* __restrict__ rank, int nEdgeThreads,
                                               const float* __restrict__ W_in, const float* __restrict__ W_l,
                                               unsigned short* __restrict__ Wt_in, unsigned short* __restrict__ Wt_l) {
    int t = blockIdx.x * 256 + threadIdx.x;
    if (t < nEdgeThreads) {
        int base = t * 16;
        if (base + 16 <= nE) {
            int4 d[4];
#pragma unroll
            for (int j = 0; j < 4; ++j) d[j] = *reinterpret_cast<const int4*>(dst + base + j * 4);
            int p[16];
#pragma unroll
            for (int j = 0; j < 4; ++j) {
                p[j * 4 + 0] = atomicAdd(&cnt[d[j].x], 1);
                p[j * 4 + 1] = atomicAdd(&cnt[d[j].y], 1);
                p[j * 4 + 2] = atomicAdd(&cnt[d[j].z], 1);
                p[j * 4 + 3] = atomicAdd(&cnt[d[j].w], 1);
            }
#pragma unroll
            for (int j = 0; j < 4; ++j)
                *reinterpret_cast<int4*>(rank + base + j * 4) =
                    make_int4(p[j * 4 + 0], p[j * 4 + 1], p[j * 4 + 2], p[j * 4 + 3]);
        } else {
            for (int e = base; e < nE; ++e) rank[e] = atomicAdd(&cnt[dst[e]], 1);
        }
        return;
    }
    int i = t - nEdgeThreads;
    if (i < 128 * 64) {
        int col = i >> 6, k = i & 63;
        Wt_in[i] = (unsigned short)f2bf(W_in[(size_t)k * HID + col]);
    } else if (i < 128 * 64 + 3 * 128 * 128) {
        int j = i - 128 * 64;
        int l = j >> 14, r = j & 16383;
        int col = r >> 7, k = r & 127;
        Wt_l[j] = (unsigned short)f2bf(W_l[(size_t)l * 16384 + (size_t)k * HID + col]);
    }
}

__global__ void k_scan1(const int* __restrict__ cnt, int n, int* __restrict__ rowp, int* __restrict__ bsum) {
    __shared__ int s[256];
    int i = blockIdx.x * 256 + threadIdx.x;
    int v = (i < n) ? cnt[i] : 0;
    s[threadIdx.x] = v;
    __syncthreads();
    for (int off = 1; off < 256; off <<= 1) {
        int t = (threadIdx.x >= off) ? s[threadIdx.x - off] : 0;
        __syncthreads();
        s[threadIdx.x] += t;
        __syncthreads();
    }
    if (i < n) rowp[i] = s[threadIdx.x] - v;  // exclusive
    if (threadIdx.x == 255) bsum[blockIdx.x] = s[255];
}

__global__ void k_scan2(int* __restrict__ bsum, int nb) {
    __shared__ int s[256];
    int v = (threadIdx.x < nb) ? bsum[threadIdx.x] : 0;
    s[threadIdx.x] = v;
    __syncthreads();
    for (int off = 1; off < 256; off <<= 1) {
        int t = (threadIdx.x >= off) ? s[threadIdx.x - off] : 0;
        __syncthreads();
        s[threadIdx.x] += t;
        __syncthreads();
    }
    if (threadIdx.x < nb) bsum[threadIdx.x] = s[threadIdx.x] - v;
}

__global__ void k_scan3(int* __restrict__ rowp, const int* __restrict__ bsum, const int* __restrict__ cnt,
                        int n, int nE, float* __restrict__ invd) {
    int i = blockIdx.x * 256 + threadIdx.x;
    if (i < n) {
        int rp = rowp[i] + bsum[blockIdx.x];
        rowp[i] = rp;
        int c = cnt[i];
        invd[i] = 1.0f / (float)(c > 1 ? c : 1);
    } else if (i == n) {
        rowp[n] = nE;
    }
}

// ---------------- atomic-free CSR fill: p = rowp[dst] + rank; nt scatter store ----------------
__global__ __launch_bounds__(256) void k_fill(const int* __restrict__ src, const int* __restrict__ dst,
                                              const int* __restrict__ rank, const int* __restrict__ rowp,
                                              int nE, int* __restrict__ csrc) {
    int t = blockIdx.x * 256 + threadIdx.x;
    int base = t * 16;
    if (base + 16 <= nE) {
        int4 d[4], s[4], r[4];
#pragma unroll
        for (int j = 0; j < 4; ++j) {
            d[j] = *reinterpret_cast<const int4*>(dst + base + j * 4);
            s[j] = *reinterpret_cast<const int4*>(src + base + j * 4);
            r[j] = *reinterpret_cast<const int4*>(rank + base + j * 4);
        }
#pragma unroll
        for (int j = 0; j < 4; ++j) {
            __builtin_nontemporal_store(s[j].x, &csrc[rowp[d[j].x] + r[j].x]);
            __builtin_nontemporal_store(s[j].y, &csrc[rowp[d[j].y] + r[j].y]);
            __builtin_nontemporal_store(s[j].z, &csrc[rowp[d[j].z] + r[j].z]);
            __builtin_nontemporal_store(s[j].w, &csrc[rowp[d[j].w] + r[j].w]);
        }
    } else if (base < nE) {
        for (int e = base; e < nE; ++e)
            __builtin_nontemporal_store(src[e], &csrc[rowp[dst[e]] + rank[e]]);
    }
}

// ---------------- in-projection (MFMA): hb = bf16(x @ W_in + b_in) ----------------
__global__ __launch_bounds__(256) void k_inproj(const float* __restrict__ x,
                                                const unsigned short* __restrict__ Wt,  // [128][64] bf16
                                                const float* __restrict__ b,
                                                unsigned* __restrict__ hout, int n) {
    __shared__ unsigned short xs[RT * INP];  // 8 KB, swizzled
    const int tid = threadIdx.x;
    const int row0 = blockIdx.x * RT;

#pragma unroll
    for (int j = 0; j < 2; ++j) {
        int fid = tid + j * 256;
        int r = fid >> 3, c = fid & 7;
        int grow = row0 + r;
        unsigned o[4] = {0, 0, 0, 0};
        if (grow < n) {
            float4 v0 = *reinterpret_cast<const float4*>(x + (size_t)grow * INP + c * 8);
            float4 v1 = *reinterpret_cast<const float4*>(x + (size_t)grow * INP + c * 8 + 4);
            o[0] = f2bf(v0.x) | (f2bf(v0.y) << 16);
            o[1] = f2bf(v0.z) | (f2bf(v0.w) << 16);
            o[2] = f2bf(v1.x) | (f2bf(v1.y) << 16);
            o[3] = f2bf(v1.z) | (f2bf(v1.w) << 16);
        }
        int sw = c ^ (r & 7);
        *reinterpret_cast<uint4*>(xs + r * INP + sw * 8) = make_uint4(o[0], o[1], o[2], o[3]);
    }
    __syncthreads();

    const int l = tid & 63;
    const int w = tid >> 6;
    const int l15 = l & 15, lg = l >> 4;
    const int xrow = w * 16 + l15;

    f32x4 acc[8];
#pragma unroll
    for (int t = 0; t < 8; ++t) acc[t] = (f32x4){0.f, 0.f, 0.f, 0.f};

#pragma unroll
    for (int kc = 0; kc < 2; ++kc) {
        int bc = (kc * 4 + lg) ^ (xrow & 7);
        bf16x8 bfrag = *reinterpret_cast<const bf16x8*>(xs + xrow * INP + bc * 8);
        const unsigned short* wp = Wt + (size_t)l15 * INP + kc * 32 + lg * 8;
        bf16x8 af[8];
#pragma unroll
        for (int t = 0; t < 8; ++t) af[t] = *reinterpret_cast<const bf16x8*>(wp + (size_t)t * 16 * INP);
#pragma unroll
        for (int t = 0; t < 8; ++t)
            acc[t] = __builtin_amdgcn_mfma_f32_16x16x32_bf16(af[t], bfrag, acc[t], 0, 0, 0);
    }

    int grow = row0 + xrow;
    if (grow < n) {
#pragma unroll
        for (int t = 0; t < 8; ++t) {
            int c0 = t * 16 + lg * 4;
            f32x4 bb = *reinterpret_cast<const f32x4*>(b + c0);
            f32x4 o = acc[t] + bb;
            uint2 p;
            p.x = f2bf(o.x) | (f2bf(o.y) << 16);
            p.y = f2bf(o.z) | (f2bf(o.w) << 16);
            *reinterpret_cast<uint2*>(hout + (size_t)grow * 64 + t * 8 + lg * 2) = p;
        }
    }
}

// ---------------- aggregation: aggx[v] = bf16( hb[v] + (sum_{u in N(v)} hb[u]) * invd[v] ), PRE-SWIZZLED ----------------
// one wave per node; lane-parallel index prefetch + __shfl broadcast -> all gathers in flight
__global__ __launch_bounds__(256) void k_agg(const unsigned* __restrict__ hb, const int* __restrict__ rowp,
                                             const int* __restrict__ csrc, const float* __restrict__ invd,
                                             unsigned* __restrict__ aggx, int n) {
    int node = blockIdx.x * 4 + (threadIdx.x >> 6);
    if (node >= n) return;
    int lane = threadIdx.x & 63;
    int e0 = rowp[node], e1 = rowp[node + 1];
    int deg = e1 - e0;
    unsigned self = hb[(size_t)node * 64 + lane];
    float inv = invd[node];
    float ax = 0.f, ay = 0.f;

    for (int base = 0; base < deg; base += 64) {
        int m = deg - base;
        if (m > 64) m = 64;
        int myidx = (base + lane < deg) ? csrc[e0 + base + lane] : 0;
        int j = 0;
        for (; j + 8 <= m; j += 8) {
            int s0 = __shfl(myidx, j + 0);
            int s1 = __shfl(myidx, j + 1);
            int s2 = __shfl(myidx, j + 2);
            int s3 = __shfl(myidx, j + 3);
            int s4 = __shfl(myidx, j + 4);
            int s5 = __shfl(myidx, j + 5);
            int s6 = __shfl(myidx, j + 6);
            int s7 = __shfl(myidx, j + 7);
            unsigned v0 = hb[(size_t)s0 * 64 + lane];
            unsigned v1 = hb[(size_t)s1 * 64 + lane];
            unsigned v2 = hb[(size_t)s2 * 64 + lane];
            unsigned v3 = hb[(size_t)s3 * 64 + lane];
            unsigned v4 = hb[(size_t)s4 * 64 + lane];
            unsigned v5 = hb[(size_t)s5 * 64 + lane];
            unsigned v6 = hb[(size_t)s6 * 64 + lane];
            unsigned v7 = hb[(size_t)s7 * 64 + lane];
            ax += ((bflo(v0) + bflo(v1)) + (bflo(v2) + bflo(v3))) +
                  ((bflo(v4) + bflo(v5)) + (bflo(v6) + bflo(v7)));
            ay += ((bfhi(v0) + bfhi(v1)) + (bfhi(v2) + bfhi(v3))) +
                  ((bfhi(v4) + bfhi(v5)) + (bfhi(v6) + bfhi(v7)));
        }
        for (; j < m; ++j) {
            int s0 = __shfl(myidx, j);
            unsigned v = hb[(size_t)s0 * 64 + lane];
            ax += bflo(v);
            ay += bfhi(v);
        }
    }

    float xlo = bflo(self) + ax * inv;
    float xhi = bfhi(self) + ay * inv;
    unsigned o = f2bf(xlo) | (f2bf(xhi) << 16);
    // swizzled position: 16B chunk c -> c ^ (row&7), within the same 256B row
    int c = lane >> 2;
    int sw = c ^ (node & 7);
    aggx[(size_t)node * 64 + sw * 4 + (lane & 3)] = o;
}

// ---------------- layer MFMA (no LDS): hout = relu(LN(X@W + b)*g + lnb) + hin ----------------
__global__ __launch_bounds__(256) void k_layer(const unsigned* __restrict__ hin,   // residual, [n*64] bf16 pairs
                                               unsigned* __restrict__ hout,
                                               const unsigned* __restrict__ aggx,  // pre-swizzled X (padded)
                                               const unsigned short* __restrict__ Wt,  // [128][128] bf16
                                               const float* __restrict__ bias, const float* __restrict__ g,
                                               const float* __restrict__ lnb, int n) {
    const int tid = threadIdx.x;
    const int row0 = blockIdx.x * RT;
    const int lane = tid & 63;
    const int w = tid >> 6;
    const int l15 = lane & 15, lg = lane >> 4;
    const int xrow = w * 16 + l15;
    const int grow = row0 + xrow;   // may be >= n for tail block; aggx is padded

    const unsigned short* xg = reinterpret_cast<const unsigned short*>(aggx) + (size_t)grow * HID;

    f32x4 acc[8];
#pragma unroll
    for (int t = 0; t < 8; ++t) acc[t] = (f32x4){0.f, 0.f, 0.f, 0.f};

#pragma unroll
    for (int kc = 0; kc < 4; ++kc) {
        int bc = (kc * 4 + lg) ^ (xrow & 7);
        bf16x8 bfrag = *reinterpret_cast<const bf16x8*>(xg + bc * 8);
        const unsigned short* wp = Wt + (size_t)l15 * HID + kc * 32 + lg * 8;
        bf16x8 af[8];
#pragma unroll
        for (int t = 0; t < 8; ++t) af[t] = *reinterpret_cast<const bf16x8*>(wp + (size_t)t * 16 * HID);
#pragma unroll
        for (int t = 0; t < 8; ++t)
            acc[t] = __builtin_amdgcn_mfma_f32_16x16x32_bf16(af[t], bfrag, acc[t], 0, 0, 0);
    }

    float s = 0.f, q = 0.f;
#pragma unroll
    for (int t = 0; t < 8; ++t) {
        int c0 = t * 16 + lg * 4;
        f32x4 bb = *reinterpret_cast<const f32x4*>(bias + c0);
        acc[t] = acc[t] + bb;
        s += acc[t].x + acc[t].y + acc[t].z + acc[t].w;
        q += acc[t].x * acc[t].x + acc[t].y * acc[t].y + acc[t].z * acc[t].z + acc[t].w * acc[t].w;
    }
    s += __shfl_xor(s, 16, 64);
    s += __shfl_xor(s, 32, 64);
    q += __shfl_xor(q, 16, 64);
    q += __shfl_xor(q, 32, 64);
    float mu = s * (1.0f / HID);
    float var = q * (1.0f / HID) - mu * mu;
    float rs = rsqrtf(var + LN_EPS);

    if (grow < n) {
#pragma unroll
        for (int t = 0; t < 8; ++t) {
            int c0 = t * 16 + lg * 4;
            uint2 rv = *reinterpret_cast<const uint2*>(hin + (size_t)grow * 64 + t * 8 + lg * 2);
            f32x4 gv = *reinterpret_cast<const f32x4*>(g + c0);
            f32x4 lb = *reinterpret_cast<const f32x4*>(lnb + c0);
            float o0 = fmaxf((acc[t].x - mu) * rs * gv.x + lb.x, 0.f) + bflo(rv.x);
            float o1 = fmaxf((acc[t].y - mu) * rs * gv.y + lb.y, 0.f) + bfhi(rv.x);
            float o2 = fmaxf((acc[t].z - mu) * rs * gv.z + lb.z, 0.f) + bflo(rv.y);
            float o3 = fmaxf((acc[t].w - mu) * rs * gv.w + lb.w, 0.f) + bfhi(rv.y);
            uint2 p;
            p.x = f2bf(o0) | (f2bf(o1) << 16);
            p.y = f2bf(o2) | (f2bf(o3) << 16);
            *reinterpret_cast<uint2*>(hout + (size_t)grow * 64 + t * 8 + lg * 2) = p;
        }
    }
}

// ---------------- final: accum[c] = sum over rows < n_act of h[r][c] ----------------
__global__ __launch_bounds__(256) void k_rowsum(const unsigned* __restrict__ hb, const int* __restrict__ n_act_p,
                                                float* __restrict__ accum, int n) {
    __shared__ float sred[256 * 2];
    int na = *n_act_p;
    int row0 = blockIdx.x * 256;
    int c = threadIdx.x & 63;    // col pair
    int sub = threadIdx.x >> 6;  // 0..3
    int rend = row0 + 256;
    if (rend > na) rend = na;
    float sx = 0.f, sy = 0.f;
    for (int r = row0 + sub; r < rend; r += 4) {
        unsigned v = hb[(size_t)r * 64 + c];
        sx += bflo(v);
        sy += bfhi(v);
    }
    sred[threadIdx.x * 2] = sx;
    sred[threadIdx.x * 2 + 1] = sy;
    __syncthreads();
    if (threadIdx.x < 64) {
        float tx = sred[threadIdx.x * 2] + sred[(threadIdx.x + 64) * 2] +
                   sred[(threadIdx.x + 128) * 2] + sred[(threadIdx.x + 192) * 2];
        float ty = sred[threadIdx.x * 2 + 1] + sred[(threadIdx.x + 64) * 2 + 1] +
                   sred[(threadIdx.x + 128) * 2 + 1] + sred[(threadIdx.x + 192) * 2 + 1];
        if (row0 < na) {
            atomicAdd(&accum[2 * threadIdx.x], tx);
            atomicAdd(&accum[2 * threadIdx.x + 1], ty);
        }
    }
}

__global__ void k_out(const float* __restrict__ accum, const int* __restrict__ n_act_p,
                      const float* __restrict__ W_out, const float* __restrict__ b_out,
                      float* __restrict__ out) {
    __shared__ float m[HID];
    int c = threadIdx.x;
    float na = (float)(*n_act_p);
    m[c] = accum[c] / na;
    __syncthreads();
    float s = b_out[c];
    for (int k = 0; k < HID; ++k) s += m[k] * W_out[k * HID + c];
    out[c] = s;
}

extern "C" void kernel_launch(void* const* d_in, const int* in_sizes, int n_in,
                              void* d_out, int out_size, void* d_ws, size_t ws_size,
                              hipStream_t stream) {
    const int n  = in_sizes[0] / INP;   // 50000
    const int nE = in_sizes[1] / 2;     // 800000
    const float* x    = (const float*)d_in[0];
    const int*   ei   = (const int*)d_in[1];
    const int*   src  = ei;
    const int*   dst  = ei + nE;
    const int*   nact = (const int*)d_in[2];
    const float* W_in = (const float*)d_in[3];
    const float* b_in = (const float*)d_in[4];
    const float* W_l  = (const float*)d_in[5];
    const float* b_l  = (const float*)d_in[6];
    const float* lng  = (const float*)d_in[7];
    const float* lnb  = (const float*)d_in[8];
    const float* W_o  = (const float*)d_in[9];
    const float* b_o  = (const float*)d_in[10];

    char* ws = (char*)d_ws;
    size_t off = 0;
    auto alloc = [&](size_t bytes) {
        void* p = ws + off;
        off = (off + bytes + 255) & ~((size_t)255);
        return p;
    };
    unsigned* hbA  = (unsigned*)alloc((size_t)n * 64 * 4);
    unsigned* hbB  = (unsigned*)alloc((size_t)n * 64 * 4);
    unsigned* aggx = (unsigned*)alloc((size_t)(n + RT) * 64 * 4);  // +RT rows pad for tail-block frag reads
    int*   cnt  = (int*)alloc((size_t)n * 4);
    int*   rowp = (int*)alloc((size_t)(n + 1) * 4);
    float* invd = (float*)alloc((size_t)n * 4);
    int*   csrc = (int*)alloc((size_t)nE * 4);
    int*   rank = (int*)alloc((size_t)nE * 4);
    int*   bsum = (int*)alloc(1024);
    float* accum = (float*)alloc(HID * 4);
    unsigned short* Wt_in = (unsigned short*)alloc(128 * 64 * 2);
    unsigned short* Wt_l  = (unsigned short*)alloc(3 * 128 * 128 * 2);

    hipMemsetAsync(cnt, 0, (size_t)n * 4, stream);
    hipMemsetAsync(accum, 0, HID * 4, stream);

    int nb = (n + 255) / 256;
    int nEdgeThreads = (nE + 15) / 16;                       // 16 edges/thread
    int nPrep = 128 * 64 + 3 * 128 * 128;
    int cpgrid = (nEdgeThreads + nPrep + 255) / 256;
    k_count<<<cpgrid, 256, 0, stream>>>(dst, nE, cnt, rank, nEdgeThreads, W_in, W_l, Wt_in, Wt_l);
    k_scan1<<<nb, 256, 0, stream>>>(cnt, n, rowp, bsum);
    k_scan2<<<1, 256, 0, stream>>>(bsum, nb);
    k_scan3<<<nb, 256, 0, stream>>>(rowp, bsum, cnt, n, nE, invd);
    k_fill<<<(nEdgeThreads + 255) / 256, 256, 0, stream>>>(src, dst, rank, rowp, nE, csrc);

    int tgrid = (n + RT - 1) / RT;
    k_inproj<<<tgrid, 256, 0, stream>>>(x, Wt_in, b_in, hbA, n);

    const unsigned* hin = hbA;
    unsigned* hout = hbB;
    for (int l = 0; l < 3; ++l) {
        k_agg<<<(n + 3) / 4, 256, 0, stream>>>(hin, rowp, csrc, invd, aggx, n);
        k_layer<<<tgrid, 256, 0, stream>>>(hin, hout, aggx,
                                           Wt_l + (size_t)l * 128 * 128,
                                           b_l + l * HID, lng + l * HID, lnb + l * HID, n);
        const unsigned* t = hout;
        hout = (unsigned*)hin;
        hin = t;
    }
    k_rowsum<<<(n + 255) / 256, 256, 0, stream>>>(hin, nact, accum, n);
    k_out<<<1, HID, 0, stream>>>(accum, nact, W_o, b_o, (float*)d_out);
}

// Round 11
// 267.722 us; speedup vs baseline: 1.3651x; 1.0982x over previous
//
#include <hip/hip_runtime.h>

#define HID 128
#define INP 64
#define LN_EPS 1e-5f
#define RT 64   // rows per block in GEMM kernels

typedef __attribute__((ext_vector_type(8))) short bf16x8;
typedef __attribute__((ext_vector_type(4))) float f32x4;

__device__ __forceinline__ unsigned f2bf(float f) {
    unsigned u = __float_as_uint(f);
    return (u + 0x7FFFu + ((u >> 16) & 1u)) >> 16;   // RNE
}
__device__ __forceinline__ float bflo(unsigned v) { return __uint_as_float(v << 16); }
__device__ __forceinline__ float bfhi(unsigned v) { return __uint_as_float(v & 0xFFFF0000u); }

// ---------------- CSR count (16 edges/thread, records per-edge rank) + fused weight prep ----------------
__global__ __launch_bounds__(256) void k_count(const int* __restrict__ dst, int nE, int* __restrict__ cnt,
                                               int* __restrict__ rank, int nEdgeThreads,
                                               const float* __restrict__ W_in, const float* __restrict__ W_l,
                                               unsigned short* __restrict__ Wt_in, unsigned short* __restrict__ Wt_l) {
    int t = blockIdx.x * 256 + threadIdx.x;
    if (t < nEdgeThreads) {
        int base = t * 16;
        if (base + 16 <= nE) {
            int4 d[4];
#pragma unroll
            for (int j = 0; j < 4; ++j) d[j] = *reinterpret_cast<const int4*>(dst + base + j * 4);
            int p[16];
#pragma unroll
            for (int j = 0; j < 4; ++j) {
                p[j * 4 + 0] = atomicAdd(&cnt[d[j].x], 1);
                p[j * 4 + 1] = atomicAdd(&cnt[d[j].y], 1);
                p[j * 4 + 2] = atomicAdd(&cnt[d[j].z], 1);
                p[j * 4 + 3] = atomicAdd(&cnt[d[j].w], 1);
            }
#pragma unroll
            for (int j = 0; j < 4; ++j)
                *reinterpret_cast<int4*>(rank + base + j * 4) =
                    make_int4(p[j * 4 + 0], p[j * 4 + 1], p[j * 4 + 2], p[j * 4 + 3]);
        } else {
            for (int e = base; e < nE; ++e) rank[e] = atomicAdd(&cnt[dst[e]], 1);
        }
        return;
    }
    int i = t - nEdgeThreads;
    if (i < 128 * 64) {
        int col = i >> 6, k = i & 63;
        Wt_in[i] = (unsigned short)f2bf(W_in[(size_t)k * HID + col]);
    } else if (i < 128 * 64 + 3 * 128 * 128) {
        int j = i - 128 * 64;
        int l = j >> 14, r = j & 16383;
        int col = r >> 7, k = r & 127;
        Wt_l[j] = (unsigned short)f2bf(W_l[(size_t)l * 16384 + (size_t)k * HID + col]);
    }
}

__global__ void k_scan1(const int* __restrict__ cnt, int n, int* __restrict__ rowp, int* __restrict__ bsum) {
    __shared__ int s[256];
    int i = blockIdx.x * 256 + threadIdx.x;
    int v = (i < n) ? cnt[i] : 0;
    s[threadIdx.x] = v;
    __syncthreads();
    for (int off = 1; off < 256; off <<= 1) {
        int t = (threadIdx.x >= off) ? s[threadIdx.x - off] : 0;
        __syncthreads();
        s[threadIdx.x] += t;
        __syncthreads();
    }
    if (i < n) rowp[i] = s[threadIdx.x] - v;  // exclusive (within block)
    if (threadIdx.x == 255) bsum[blockIdx.x] = s[255];
}

// scan3 with inline redundant scan of bsum (replaces scan2)
__global__ void k_scan3(int* __restrict__ rowp, const int* __restrict__ bsum, const int* __restrict__ cnt,
                        int n, int nE, float* __restrict__ invd, int nb) {
    __shared__ int s[256];
    __shared__ int boff;
    int v = (threadIdx.x < nb) ? bsum[threadIdx.x] : 0;
    s[threadIdx.x] = v;
    __syncthreads();
    for (int off = 1; off < 256; off <<= 1) {
        int t = (threadIdx.x >= off) ? s[threadIdx.x - off] : 0;
        __syncthreads();
        s[threadIdx.x] += t;
        __syncthreads();
    }
    if (threadIdx.x == blockIdx.x) boff = s[threadIdx.x] - v;  // exclusive prefix for this block
    __syncthreads();
    int i = blockIdx.x * 256 + threadIdx.x;
    if (i < n) {
        rowp[i] += boff;
        int c = cnt[i];
        invd[i] = 1.0f / (float)(c > 1 ? c : 1);
    } else if (i == n) {
        rowp[n] = nE;
    }
}

// ---------------- fused: [0,tgrid) in-projection MFMA; [tgrid,..) atomic-free CSR fill ----------------
__global__ __launch_bounds__(256) void k_fillproj(const float* __restrict__ x,
                                                  const unsigned short* __restrict__ Wt,  // [128][64] bf16
                                                  const float* __restrict__ b,
                                                  unsigned* __restrict__ hout, int n, int tgrid,
                                                  const int* __restrict__ src, const int* __restrict__ dst,
                                                  const int* __restrict__ rank, const int* __restrict__ rowp,
                                                  int nE, int* __restrict__ csrc) {
    const int tid = threadIdx.x;
    if (blockIdx.x >= tgrid) {
        // ---- CSR fill: p = rowp[dst] + rank; nt scatter store ----
        int t = (blockIdx.x - tgrid) * 256 + tid;
        int base = t * 16;
        if (base + 16 <= nE) {
            int4 d[4], s[4], r[4];
#pragma unroll
            for (int j = 0; j < 4; ++j) {
                d[j] = *reinterpret_cast<const int4*>(dst + base + j * 4);
                s[j] = *reinterpret_cast<const int4*>(src + base + j * 4);
                r[j] = *reinterpret_cast<const int4*>(rank + base + j * 4);
            }
#pragma unroll
            for (int j = 0; j < 4; ++j) {
                __builtin_nontemporal_store(s[j].x, &csrc[rowp[d[j].x] + r[j].x]);
                __builtin_nontemporal_store(s[j].y, &csrc[rowp[d[j].y] + r[j].y]);
                __builtin_nontemporal_store(s[j].z, &csrc[rowp[d[j].z] + r[j].z]);
                __builtin_nontemporal_store(s[j].w, &csrc[rowp[d[j].w] + r[j].w]);
            }
        } else if (base < nE) {
            for (int e = base; e < nE; ++e)
                __builtin_nontemporal_store(src[e], &csrc[rowp[dst[e]] + rank[e]]);
        }
        return;
    }
    // ---- in-projection ----
    __shared__ unsigned short xs[RT * INP];  // 8 KB, swizzled
    const int row0 = blockIdx.x * RT;
#pragma unroll
    for (int j = 0; j < 2; ++j) {
        int fid = tid + j * 256;
        int r = fid >> 3, c = fid & 7;
        int grow = row0 + r;
        unsigned o[4] = {0, 0, 0, 0};
        if (grow < n) {
            float4 v0 = *reinterpret_cast<const float4*>(x + (size_t)grow * INP + c * 8);
            float4 v1 = *reinterpret_cast<const float4*>(x + (size_t)grow * INP + c * 8 + 4);
            o[0] = f2bf(v0.x) | (f2bf(v0.y) << 16);
            o[1] = f2bf(v0.z) | (f2bf(v0.w) << 16);
            o[2] = f2bf(v1.x) | (f2bf(v1.y) << 16);
            o[3] = f2bf(v1.z) | (f2bf(v1.w) << 16);
        }
        int sw = c ^ (r & 7);
        *reinterpret_cast<uint4*>(xs + r * INP + sw * 8) = make_uint4(o[0], o[1], o[2], o[3]);
    }
    __syncthreads();

    const int l = tid & 63;
    const int w = tid >> 6;
    const int l15 = l & 15, lg = l >> 4;
    const int xrow = w * 16 + l15;

    f32x4 acc[8];
#pragma unroll
    for (int t = 0; t < 8; ++t) acc[t] = (f32x4){0.f, 0.f, 0.f, 0.f};

#pragma unroll
    for (int kc = 0; kc < 2; ++kc) {
        int bc = (kc * 4 + lg) ^ (xrow & 7);
        bf16x8 bfrag = *reinterpret_cast<const bf16x8*>(xs + xrow * INP + bc * 8);
        const unsigned short* wp = Wt + (size_t)l15 * INP + kc * 32 + lg * 8;
        bf16x8 af[8];
#pragma unroll
        for (int t = 0; t < 8; ++t) af[t] = *reinterpret_cast<const bf16x8*>(wp + (size_t)t * 16 * INP);
#pragma unroll
        for (int t = 0; t < 8; ++t)
            acc[t] = __builtin_amdgcn_mfma_f32_16x16x32_bf16(af[t], bfrag, acc[t], 0, 0, 0);
    }

    int grow = row0 + xrow;
    if (grow < n) {
#pragma unroll
        for (int t = 0; t < 8; ++t) {
            int c0 = t * 16 + lg * 4;
            f32x4 bb = *reinterpret_cast<const f32x4*>(b + c0);
            f32x4 o = acc[t] + bb;
            uint2 p;
            p.x = f2bf(o.x) | (f2bf(o.y) << 16);
            p.y = f2bf(o.z) | (f2bf(o.w) << 16);
            *reinterpret_cast<uint2*>(hout + (size_t)grow * 64 + t * 8 + lg * 2) = p;
        }
    }
}

// ---------------- aggregation (uint4 gather: 4 edges/wave-instruction) ----------------
// aggx[v] = bf16( hb[v] + (sum_{u in N(v)} hb[u]) * invd[v] ), PRE-SWIZZLED
__global__ __launch_bounds__(256) void k_agg(const unsigned* __restrict__ hb, const int* __restrict__ rowp,
                                             const int* __restrict__ csrc, const float* __restrict__ invd,
                                             unsigned* __restrict__ aggx, int n) {
    int node = blockIdx.x * 4 + (threadIdx.x >> 6);
    if (node >= n) return;
    int lane = threadIdx.x & 63;
    int grp = lane >> 4, cidx = lane & 15;
    int e0 = rowp[node], e1 = rowp[node + 1];
    int deg = e1 - e0;
    const uint4* hb4 = reinterpret_cast<const uint4*>(hb);
    float a0 = 0, a1 = 0, a2 = 0, a3 = 0, a4 = 0, a5 = 0, a6 = 0, a7 = 0;

    for (int base = 0; base < deg; base += 64) {
        int m = deg - base;
        if (m > 64) m = 64;
        int myidx = (base + lane < deg) ? csrc[e0 + base + lane] : 0;
        int steps = (m + 3) >> 2;   // groups of 4 edges
        int jj = 0;
        for (; jj + 4 <= steps; jj += 4) {
            uint4 v[4];
#pragma unroll
            for (int k = 0; k < 4; ++k) {
                int ei = (jj + k) * 4 + grp;
                int s = __shfl(myidx, ei);
                v[k] = (ei < m) ? hb4[(size_t)s * 16 + cidx] : make_uint4(0, 0, 0, 0);
            }
#pragma unroll
            for (int k = 0; k < 4; ++k) {
                a0 += bflo(v[k].x); a1 += bfhi(v[k].x);
                a2 += bflo(v[k].y); a3 += bfhi(v[k].y);
                a4 += bflo(v[k].z); a5 += bfhi(v[k].z);
                a6 += bflo(v[k].w); a7 += bfhi(v[k].w);
            }
        }
        for (; jj < steps; ++jj) {
            int ei = jj * 4 + grp;
            int s = __shfl(myidx, ei);
            if (ei < m) {
                uint4 v = hb4[(size_t)s * 16 + cidx];
                a0 += bflo(v.x); a1 += bfhi(v.x);
                a2 += bflo(v.y); a3 += bfhi(v.y);
                a4 += bflo(v.z); a5 += bfhi(v.z);
                a6 += bflo(v.w); a7 += bfhi(v.w);
            }
        }
    }
    // reduce across the 4 edge-groups (lanes xor 16, 32 hold same column chunk)
    a0 += __shfl_xor(a0, 16, 64); a0 += __shfl_xor(a0, 32, 64);
    a1 += __shfl_xor(a1, 16, 64); a1 += __shfl_xor(a1, 32, 64);
    a2 += __shfl_xor(a2, 16, 64); a2 += __shfl_xor(a2, 32, 64);
    a3 += __shfl_xor(a3, 16, 64); a3 += __shfl_xor(a3, 32, 64);
    a4 += __shfl_xor(a4, 16, 64); a4 += __shfl_xor(a4, 32, 64);
    a5 += __shfl_xor(a5, 16, 64); a5 += __shfl_xor(a5, 32, 64);
    a6 += __shfl_xor(a6, 16, 64); a6 += __shfl_xor(a6, 32, 64);
    a7 += __shfl_xor(a7, 16, 64); a7 += __shfl_xor(a7, 32, 64);

    if (grp == 0) {  // lanes 0..15 write the full row
        float inv = invd[node];
        uint4 self = hb4[(size_t)node * 16 + cidx];
        unsigned o0 = f2bf(bflo(self.x) + a0 * inv) | (f2bf(bfhi(self.x) + a1 * inv) << 16);
        unsigned o1 = f2bf(bflo(self.y) + a2 * inv) | (f2bf(bfhi(self.y) + a3 * inv) << 16);
        unsigned o2 = f2bf(bflo(self.z) + a4 * inv) | (f2bf(bfhi(self.z) + a5 * inv) << 16);
        unsigned o3 = f2bf(bflo(self.w) + a6 * inv) | (f2bf(bfhi(self.w) + a7 * inv) << 16);
        int sw = cidx ^ (node & 7);  // 16B chunk swizzle within the 256B row
        *reinterpret_cast<uint4*>(aggx + (size_t)node * 64 + sw * 4) = make_uint4(o0, o1, o2, o3);
    }
}

// ---------------- layer MFMA (no LDS): hout = relu(LN(X@W + b)*g + lnb) + hin ----------------
__global__ __launch_bounds__(256) void k_layer(const unsigned* __restrict__ hin,
                                               unsigned* __restrict__ hout,
                                               const unsigned* __restrict__ aggx,
                                               const unsigned short* __restrict__ Wt,
                                               const float* __restrict__ bias, const float* __restrict__ g,
                                               const float* __restrict__ lnb, int n) {
    const int tid = threadIdx.x;
    const int row0 = blockIdx.x * RT;
    const int lane = tid & 63;
    const int w = tid >> 6;
    const int l15 = lane & 15, lg = lane >> 4;
    const int xrow = w * 16 + l15;
    const int grow = row0 + xrow;

    const unsigned short* xg = reinterpret_cast<const unsigned short*>(aggx) + (size_t)grow * HID;

    f32x4 acc[8];
#pragma unroll
    for (int t = 0; t < 8; ++t) acc[t] = (f32x4){0.f, 0.f, 0.f, 0.f};

#pragma unroll
    for (int kc = 0; kc < 4; ++kc) {
        int bc = (kc * 4 + lg) ^ (xrow & 7);
        bf16x8 bfrag = *reinterpret_cast<const bf16x8*>(xg + bc * 8);
        const unsigned short* wp = Wt + (size_t)l15 * HID + kc * 32 + lg * 8;
        bf16x8 af[8];
#pragma unroll
        for (int t = 0; t < 8; ++t) af[t] = *reinterpret_cast<const bf16x8*>(wp + (size_t)t * 16 * HID);
#pragma unroll
        for (int t = 0; t < 8; ++t)
            acc[t] = __builtin_amdgcn_mfma_f32_16x16x32_bf16(af[t], bfrag, acc[t], 0, 0, 0);
    }

    float s = 0.f, q = 0.f;
#pragma unroll
    for (int t = 0; t < 8; ++t) {
        int c0 = t * 16 + lg * 4;
        f32x4 bb = *reinterpret_cast<const f32x4*>(bias + c0);
        acc[t] = acc[t] + bb;
        s += acc[t].x + acc[t].y + acc[t].z + acc[t].w;
        q += acc[t].x * acc[t].x + acc[t].y * acc[t].y + acc[t].z * acc[t].z + acc[t].w * acc[t].w;
    }
    s += __shfl_xor(s, 16, 64);
    s += __shfl_xor(s, 32, 64);
    q += __shfl_xor(q, 16, 64);
    q += __shfl_xor(q, 32, 64);
    float mu = s * (1.0f / HID);
    float var = q * (1.0f / HID) - mu * mu;
    float rs = rsqrtf(var + LN_EPS);

    if (grow < n) {
#pragma unroll
        for (int t = 0; t < 8; ++t) {
            int c0 = t * 16 + lg * 4;
            uint2 rv = *reinterpret_cast<const uint2*>(hin + (size_t)grow * 64 + t * 8 + lg * 2);
            f32x4 gv = *reinterpret_cast<const f32x4*>(g + c0);
            f32x4 lb = *reinterpret_cast<const f32x4*>(lnb + c0);
            float o0 = fmaxf((acc[t].x - mu) * rs * gv.x + lb.x, 0.f) + bflo(rv.x);
            float o1 = fmaxf((acc[t].y - mu) * rs * gv.y + lb.y, 0.f) + bfhi(rv.x);
            float o2 = fmaxf((acc[t].z - mu) * rs * gv.z + lb.z, 0.f) + bflo(rv.y);
            float o3 = fmaxf((acc[t].w - mu) * rs * gv.w + lb.w, 0.f) + bfhi(rv.y);
            uint2 p;
            p.x = f2bf(o0) | (f2bf(o1) << 16);
            p.y = f2bf(o2) | (f2bf(o3) << 16);
            *reinterpret_cast<uint2*>(hout + (size_t)grow * 64 + t * 8 + lg * 2) = p;
        }
    }
}

// ---------------- FINAL layer: same as k_layer but fuses the masked column-sum; no hout write ----------------
__global__ __launch_bounds__(256) void k_layerF(const unsigned* __restrict__ hin,
                                                const unsigned* __restrict__ aggx,
                                                const unsigned short* __restrict__ Wt,
                                                const float* __restrict__ bias, const float* __restrict__ g,
                                                const float* __restrict__ lnb,
                                                const int* __restrict__ n_act_p,
                                                float* __restrict__ accum) {
    __shared__ float red[4][4][8][4];   // [wave][lg][t][j] = 2 KB
    const int tid = threadIdx.x;
    const int row0 = blockIdx.x * RT;
    const int lane = tid & 63;
    const int w = tid >> 6;
    const int l15 = lane & 15, lg = lane >> 4;
    const int xrow = w * 16 + l15;
    const int grow = row0 + xrow;
    const int na = *n_act_p;

    const unsigned short* xg = reinterpret_cast<const unsigned short*>(aggx) + (size_t)grow * HID;

    f32x4 acc[8];
#pragma unroll
    for (int t = 0; t < 8; ++t) acc[t] = (f32x4){0.f, 0.f, 0.f, 0.f};

#pragma unroll
    for (int kc = 0; kc < 4; ++kc) {
        int bc = (kc * 4 + lg) ^ (xrow & 7);
        bf16x8 bfrag = *reinterpret_cast<const bf16x8*>(xg + bc * 8);
        const unsigned short* wp = Wt + (size_t)l15 * HID + kc * 32 + lg * 8;
        bf16x8 af[8];
#pragma unroll
        for (int t = 0; t < 8; ++t) af[t] = *reinterpret_cast<const bf16x8*>(wp + (size_t)t * 16 * HID);
#pragma unroll
        for (int t = 0; t < 8; ++t)
            acc[t] = __builtin_amdgcn_mfma_f32_16x16x32_bf16(af[t], bfrag, acc[t], 0, 0, 0);
    }

    float s = 0.f, q = 0.f;
#pragma unroll
    for (int t = 0; t < 8; ++t) {
        int c0 = t * 16 + lg * 4;
        f32x4 bb = *reinterpret_cast<const f32x4*>(bias + c0);
        acc[t] = acc[t] + bb;
        s += acc[t].x + acc[t].y + acc[t].z + acc[t].w;
        q += acc[t].x * acc[t].x + acc[t].y * acc[t].y + acc[t].z * acc[t].z + acc[t].w * acc[t].w;
    }
    s += __shfl_xor(s, 16, 64);
    s += __shfl_xor(s, 32, 64);
    q += __shfl_xor(q, 16, 64);
    q += __shfl_xor(q, 32, 64);
    float mu = s * (1.0f / HID);
    float var = q * (1.0f / HID) - mu * mu;
    float rs = rsqrtf(var + LN_EPS);

    const float msk = (grow < na) ? 1.f : 0.f;   // rows >= na (incl. tail garbage) contribute 0
#pragma unroll
    for (int t = 0; t < 8; ++t) {
        int c0 = t * 16 + lg * 4;
        // residual read is in-bounds of the workspace even for tail rows; value masked below
        uint2 rv = *reinterpret_cast<const uint2*>(hin + (size_t)grow * 64 + t * 8 + lg * 2);
        f32x4 gv = *reinterpret_cast<const f32x4*>(g + c0);
        f32x4 lb = *reinterpret_cast<const f32x4*>(lnb + c0);
        float o0 = (fmaxf((acc[t].x - mu) * rs * gv.x + lb.x, 0.f) + bflo(rv.x)) * msk;
        float o1 = (fmaxf((acc[t].y - mu) * rs * gv.y + lb.y, 0.f) + bfhi(rv.x)) * msk;
        float o2 = (fmaxf((acc[t].z - mu) * rs * gv.z + lb.z, 0.f) + bflo(rv.y)) * msk;
        float o3 = (fmaxf((acc[t].w - mu) * rs * gv.w + lb.w, 0.f) + bfhi(rv.y)) * msk;
        // sum over the 16 rows covered by l15 lanes
#pragma unroll
        for (int m = 1; m < 16; m <<= 1) {
            o0 += __shfl_xor(o0, m, 64);
            o1 += __shfl_xor(o1, m, 64);
            o2 += __shfl_xor(o2, m, 64);
            o3 += __shfl_xor(o3, m, 64);
        }
        if (l15 == 0) {
            red[w][lg][t][0] = o0;
            red[w][lg][t][1] = o1;
            red[w][lg][t][2] = o2;
            red[w][lg][t][3] = o3;
        }
    }
    __syncthreads();
    if (tid < HID) {
        int t = tid >> 4, rem = tid & 15;
        int lgq = rem >> 2, j = rem & 3;
        float v = red[0][lgq][t][j] + red[1][lgq][t][j] + red[2][lgq][t][j] + red[3][lgq][t][j];
        atomicAdd(&accum[tid], v);
    }
}

__global__ void k_out(const float* __restrict__ accum, const int* __restrict__ n_act_p,
                      const float* __restrict__ W_out, const float* __restrict__ b_out,
                      float* __restrict__ out) {
    __shared__ float m[HID];
    int c = threadIdx.x;
    float na = (float)(*n_act_p);
    m[c] = accum[c] / na;
    __syncthreads();
    float s = b_out[c];
    for (int k = 0; k < HID; ++k) s += m[k] * W_out[k * HID + c];
    out[c] = s;
}

extern "C" void kernel_launch(void* const* d_in, const int* in_sizes, int n_in,
                              void* d_out, int out_size, void* d_ws, size_t ws_size,
                              hipStream_t stream) {
    const int n  = in_sizes[0] / INP;   // 50000
    const int nE = in_sizes[1] / 2;     // 800000
    const float* x    = (const float*)d_in[0];
    const int*   ei   = (const int*)d_in[1];
    const int*   src  = ei;
    const int*   dst  = ei + nE;
    const int*   nact = (const int*)d_in[2];
    const float* W_in = (const float*)d_in[3];
    const float* b_in = (const float*)d_in[4];
    const float* W_l  = (const float*)d_in[5];
    const float* b_l  = (const float*)d_in[6];
    const float* lng  = (const float*)d_in[7];
    const float* lnb  = (const float*)d_in[8];
    const float* W_o  = (const float*)d_in[9];
    const float* b_o  = (const float*)d_in[10];

    char* ws = (char*)d_ws;
    size_t off = 0;
    auto alloc = [&](size_t bytes) {
        void* p = ws + off;
        off = (off + bytes + 255) & ~((size_t)255);
        return p;
    };
    unsigned* hbA  = (unsigned*)alloc((size_t)n * 64 * 4);
    unsigned* hbB  = (unsigned*)alloc((size_t)n * 64 * 4);
    unsigned* aggx = (unsigned*)alloc((size_t)(n + RT) * 64 * 4);  // +RT rows pad for tail-block frag reads
    size_t cntBytes = (((size_t)n * 4) + 255) & ~((size_t)255);
    int*   cnt   = (int*)alloc(cntBytes);
    float* accum = (float*)alloc(HID * 4);   // adjacent to cnt -> one memset covers both
    int*   rowp = (int*)alloc((size_t)(n + 1) * 4);
    float* invd = (float*)alloc((size_t)n * 4);
    int*   csrc = (int*)alloc((size_t)nE * 4);
    int*   rank = (int*)alloc((size_t)nE * 4);
    int*   bsum = (int*)alloc(1024);
    unsigned short* Wt_in = (unsigned short*)alloc(128 * 64 * 2);
    unsigned short* Wt_l  = (unsigned short*)alloc(3 * 128 * 128 * 2);

    hipMemsetAsync(cnt, 0, cntBytes + HID * 4, stream);

    int nb = (n + 255) / 256;
    int nEdgeThreads = (nE + 15) / 16;                       // 16 edges/thread
    int nPrep = 128 * 64 + 3 * 128 * 128;
    int cpgrid = (nEdgeThreads + nPrep + 255) / 256;
    k_count<<<cpgrid, 256, 0, stream>>>(dst, nE, cnt, rank, nEdgeThreads, W_in, W_l, Wt_in, Wt_l);
    k_scan1<<<nb, 256, 0, stream>>>(cnt, n, rowp, bsum);
    k_scan3<<<nb, 256, 0, stream>>>(rowp, bsum, cnt, n, nE, invd, nb);

    int tgrid = (n + RT - 1) / RT;
    int fgrid = (nEdgeThreads + 255) / 256;
    k_fillproj<<<tgrid + fgrid, 256, 0, stream>>>(x, Wt_in, b_in, hbA, n, tgrid,
                                                  src, dst, rank, rowp, nE, csrc);

    const unsigned* hin = hbA;
    unsigned* hout = hbB;
    for (int l = 0; l < 3; ++l) {
        k_agg<<<(n + 3) / 4, 256, 0, stream>>>(hin, rowp, csrc, invd, aggx, n);
        if (l < 2) {
            k_layer<<<tgrid, 256, 0, stream>>>(hin, hout, aggx,
                                               Wt_l + (size_t)l * 128 * 128,
                                               b_l + l * HID, lng + l * HID, lnb + l * HID, n);
            const unsigned* t = hout;
            hout = (unsigned*)hin;
            hin = t;
        } else {
            k_layerF<<<tgrid, 256, 0, stream>>>(hin, aggx,
                                                Wt_l + (size_t)l * 128 * 128,
                                                b_l + l * HID, lng + l * HID, lnb + l * HID,
                                                nact, accum);
        }
    }
    k_out<<<1, HID, 0, stream>>>(accum, nact, W_o, b_o, (float*)d_out);
}